// Round 1
// 1144.392 us; speedup vs baseline: 1.4013x; 1.4013x over previous
//
#include <hip/hip_runtime.h>
#include <hip/hip_bf16.h>
#include <math.h>

#define Bb 2
#define Ss 2048
#define Dd 1024
#define Hh 16
#define DH 64
#define Ee 8
#define FH 4096
#define Tt (Bb*Ss)

typedef __attribute__((ext_vector_type(8))) short short8;
typedef __attribute__((ext_vector_type(4))) short short4v;
typedef __attribute__((ext_vector_type(4))) float float4v;

#define AS 40   // LDS row stride (bf16) for GEMM tiles

static __device__ inline short f2bf(float f) {
    __hip_bfloat16 h = __float2bfloat16(f);
    return *reinterpret_cast<short*>(&h);
}

// ---------------------------------------------------------------------------
// LayerNorm -> bf16. One block (256 thr) per token.
__global__ __launch_bounds__(256) void ln_kernel(const float* __restrict__ x,
                                                 const float* __restrict__ sc,
                                                 const float* __restrict__ bi,
                                                 __hip_bfloat16* __restrict__ y) {
    int t = blockIdx.x, tid = threadIdx.x;
    const float* xr = x + (size_t)t * Dd;
    float s1 = 0.f, s2 = 0.f;
    for (int d = tid; d < Dd; d += 256) { float v = xr[d]; s1 += v; s2 += v * v; }
    __shared__ float r1[256], r2[256];
    r1[tid] = s1; r2[tid] = s2; __syncthreads();
    for (int off = 128; off > 0; off >>= 1) {
        if (tid < off) { r1[tid] += r1[tid + off]; r2[tid] += r2[tid + off]; }
        __syncthreads();
    }
    float mu = r1[0] * (1.f / Dd);
    float var = r2[0] * (1.f / Dd) - mu * mu;
    float rstd = rsqrtf(var + 1e-6f);
    __hip_bfloat16* yr = y + (size_t)t * Dd;
    for (int d = tid; d < Dd; d += 256) {
        float v = xr[d];
        yr[d] = __float2bfloat16((v - mu) * rstd * sc[d] + bi[d]);
    }
}

// ---------------------------------------------------------------------------
// Transpose+convert fp32 [K][N] -> bf16 [N][K]. z selects among 4 (QKVO).
__global__ __launch_bounds__(256) void transpose_qkvo(
    const float* W0, const float* W1, const float* W2, const float* W3,
    __hip_bfloat16* T0, __hip_bfloat16* T1, __hip_bfloat16* T2, __hip_bfloat16* T3) {
    int z = blockIdx.z;
    const float* W = (z == 0) ? W0 : (z == 1) ? W1 : (z == 2) ? W2 : W3;
    __hip_bfloat16* Wt = (z == 0) ? T0 : (z == 1) ? T1 : (z == 2) ? T2 : T3;
    __shared__ float tile[32][33];
    int k0 = blockIdx.y * 32, n0 = blockIdx.x * 32;
    int tx = threadIdx.x & 31, ty = threadIdx.x >> 5;
    #pragma unroll
    for (int p = 0; p < 4; p++)
        tile[ty + p * 8][tx] = W[(size_t)(k0 + ty + p * 8) * Dd + n0 + tx];
    __syncthreads();
    #pragma unroll
    for (int p = 0; p < 4; p++)
        Wt[(size_t)(n0 + ty + p * 8) * Dd + k0 + tx] = __float2bfloat16(tile[tx][ty + p * 8]);
}

// Batched expert-weight transpose: W[e] fp32 [K][N] -> Wt[e] bf16 [N][K]
__global__ __launch_bounds__(256) void transpose_we(const float* __restrict__ W,
                                                    __hip_bfloat16* __restrict__ Wt,
                                                    int Kd, int N) {
    int e = blockIdx.z;
    W  += (size_t)e * Kd * N;
    Wt += (size_t)e * Kd * N;
    __shared__ float tile[32][33];
    int k0 = blockIdx.y * 32, n0 = blockIdx.x * 32;
    int tx = threadIdx.x & 31, ty = threadIdx.x >> 5;
    #pragma unroll
    for (int p = 0; p < 4; p++)
        tile[ty + p * 8][tx] = W[(size_t)(k0 + ty + p * 8) * N + n0 + tx];
    __syncthreads();
    #pragma unroll
    for (int p = 0; p < 4; p++)
        Wt[(size_t)(n0 + ty + p * 8) * Kd + k0 + tx] = __float2bfloat16(tile[tx][ty + p * 8]);
}

// ---------------------------------------------------------------------------
// bf16 MFMA GEMM, tile 128x128, BK=32. Bt is [N][K] bf16.
// MODE 0: plain -> bf16 C
// MODE 1: + residual fp32 -> fp32 C  (Wo)
// MODE 2: expert GEMM1: gather A rows via bucket, gelu -> Hbuf[base[e]+m] bf16
// MODE 3: expert GEMM2: A = H + base[e], plain fp32 -> O2[base[e]+m]
// MODE 4: V projection -> Vt[b][h][d][s] bf16 (transposed write)
template<int MODE>
__global__ __launch_bounds__(256) void gemm_mfma(
    const __hip_bfloat16* __restrict__ A, const __hip_bfloat16* __restrict__ Bt,
    const float* __restrict__ bias, void* __restrict__ Cv,
    int M, int N, int Kd,
    const int* __restrict__ bucket, const int* __restrict__ cnts,
    const int* __restrict__ bases, const float* __restrict__ residual)
{
    int Me = M;
    const int* rowIdx = nullptr;
    int hbase = 0;
    if (MODE == 2 || MODE == 3) {
        int e = blockIdx.z;
        Me = cnts[e];
        hbase = bases[e];
        Bt += (size_t)e * N * Kd;
        bias += (size_t)e * N;
        if (MODE == 2) rowIdx = bucket + e * Tt;
        if (MODE == 3) A += (size_t)hbase * Kd;
    }
    int m0 = blockIdx.y * 128;
    if (m0 >= Me) return;
    int n0 = blockIdx.x * 128;

    __shared__ __hip_bfloat16 As[128 * AS];
    __shared__ __hip_bfloat16 Bs[128 * AS];

    int tid = threadIdx.x;
    int lane = tid & 63, wave = tid >> 6;
    int wm = (wave & 1) * 64, wn = (wave >> 1) * 64;
    int quad = lane >> 4, l16 = lane & 15;
    int srow = tid >> 2;
    int skg = (tid & 3) * 8;

    float4v acc[4][4];
    #pragma unroll
    for (int i = 0; i < 4; i++)
        #pragma unroll
        for (int j = 0; j < 4; j++) acc[i][j] = (float4v)0.f;

    for (int k0 = 0; k0 < Kd; k0 += 32) {
        #pragma unroll
        for (int p = 0; p < 2; p++) {
            int r = srow + p * 64;
            int gm = m0 + r;
            short8 va = (short8)0;
            if (gm < Me) {
                int row = (MODE == 2) ? rowIdx[gm] : gm;
                va = *(const short8*)(A + (size_t)row * Kd + k0 + skg);
            }
            *(short8*)(&As[r * AS + skg]) = va;
            short8 vb = *(const short8*)(Bt + (size_t)(n0 + r) * Kd + k0 + skg);
            *(short8*)(&Bs[r * AS + skg]) = vb;
        }
        __syncthreads();
        short8 af[4], bf[4];
        #pragma unroll
        for (int i = 0; i < 4; i++)
            af[i] = *(const short8*)(&As[(wm + i * 16 + l16) * AS + quad * 8]);
        #pragma unroll
        for (int j = 0; j < 4; j++)
            bf[j] = *(const short8*)(&Bs[(wn + j * 16 + l16) * AS + quad * 8]);
        #pragma unroll
        for (int i = 0; i < 4; i++)
            #pragma unroll
            for (int j = 0; j < 4; j++)
                acc[i][j] = __builtin_amdgcn_mfma_f32_16x16x32_bf16(af[i], bf[j], acc[i][j], 0, 0, 0);
        __syncthreads();
    }

    #pragma unroll
    for (int i = 0; i < 4; i++) {
        #pragma unroll
        for (int j = 0; j < 4; j++) {
            int col = n0 + wn + j * 16 + l16;
            float bsv = bias[col];
            if (MODE == 4) {
                // tokens m..m+3 consecutive -> pack 4 bf16, store 8B to Vt[b][h][d][s]
                int mb = m0 + wm + i * 16 + quad * 4;
                int b = mb >> 11, s0 = mb & (Ss - 1);
                int h = col >> 6, d = col & (DH - 1);
                short4v pk;
                #pragma unroll
                for (int r = 0; r < 4; r++) pk[r] = f2bf(acc[i][j][r] + bsv);
                *(short4v*)((__hip_bfloat16*)Cv + ((size_t)(b * Hh + h) * DH + d) * Ss + s0) = pk;
                continue;
            }
            #pragma unroll
            for (int r = 0; r < 4; r++) {
                int m = m0 + wm + i * 16 + quad * 4 + r;
                if (m >= Me) continue;
                float val = acc[i][j][r] + bsv;
                if (MODE == 0) {
                    ((__hip_bfloat16*)Cv)[(size_t)m * N + col] = __float2bfloat16(val);
                } else if (MODE == 1) {
                    ((float*)Cv)[(size_t)m * N + col] = val + residual[(size_t)m * N + col];
                } else if (MODE == 2) {
                    float th = tanhf(0.7978845608028654f * (val + 0.044715f * val * val * val));
                    ((__hip_bfloat16*)Cv)[(size_t)(hbase + m) * N + col] =
                        __float2bfloat16(0.5f * val * (1.f + th));
                } else { // MODE 3
                    ((float*)Cv)[(size_t)(hbase + m) * N + col] = val;
                }
            }
        }
    }
}

// ---------------------------------------------------------------------------
// MFMA flash attention. Block = 4 waves; wave owns 16 queries; no LDS/barriers.
// S^T = K·Q^T (C: col=query, row=key), fixed-shift exp, shfl into P A-frag,
// O += P·V^T with Vt[b][h][d][s].
__global__ __launch_bounds__(256) void attn_mfma(const __hip_bfloat16* __restrict__ q,
                                                 const __hip_bfloat16* __restrict__ k,
                                                 const __hip_bfloat16* __restrict__ Vt,
                                                 __hip_bfloat16* __restrict__ out) {
    int h = blockIdx.y, b = blockIdx.z;
    int wave = threadIdx.x >> 6, lane = threadIdx.x & 63;
    int quad = lane >> 4, l16 = lane & 15;
    int q0 = blockIdx.x * 64 + wave * 16;
    int tb = b * Ss;

    // Q B-fragments (n=query, k=dim)
    const __hip_bfloat16* qp = q + (size_t)(tb + q0 + l16) * (Hh * DH) + h * DH + quad * 8;
    short8 qf0 = *(const short8*)(qp);
    short8 qf1 = *(const short8*)(qp + 32);

    float4v oc[4];
    #pragma unroll
    for (int i = 0; i < 4; i++) oc[i] = (float4v)0.f;
    float lsum = 0.f;

    const __hip_bfloat16* vbase = Vt + ((size_t)(b * Hh + h) * DH) * Ss;
    int qglob = q0 + l16;
    int srcA = (quad & 1) * 32 + l16;
    int srcB = srcA + 16;
    int sel = quad >> 1;
    int nsteps = (q0 + 47) >> 5;

    for (int st = 0; st < nsteps; st++) {
        int k0 = st * 32;
        const __hip_bfloat16* kp = k + (size_t)(tb + k0 + l16) * (Hh * DH) + h * DH + quad * 8;
        short8 a0 = *(const short8*)(kp);
        short8 a1 = *(const short8*)(kp + 32);
        short8 a2 = *(const short8*)(kp + (size_t)16 * (Hh * DH));
        short8 a3 = *(const short8*)(kp + (size_t)16 * (Hh * DH) + 32);

        float4v c0 = (float4v)0.f, c1 = (float4v)0.f;
        c0 = __builtin_amdgcn_mfma_f32_16x16x32_bf16(a0, qf0, c0, 0, 0, 0);
        c0 = __builtin_amdgcn_mfma_f32_16x16x32_bf16(a1, qf1, c0, 0, 0, 0);
        c1 = __builtin_amdgcn_mfma_f32_16x16x32_bf16(a2, qf0, c1, 0, 0, 0);
        c1 = __builtin_amdgcn_mfma_f32_16x16x32_bf16(a3, qf1, c1, 0, 0, 0);

        float p0[4], p1[4];
        #pragma unroll
        for (int r = 0; r < 4; r++) {
            int key0 = k0 + quad * 4 + r;
            int key1 = key0 + 16;
            p0[r] = (key0 <= qglob) ? __expf(c0[r] * 0.125f - 4.f) : 0.f;
            p1[r] = (key1 <= qglob) ? __expf(c1[r] * 0.125f - 4.f) : 0.f;
            lsum += p0[r] + p1[r];
        }

        short8 pf;
        #pragma unroll
        for (int r = 0; r < 4; r++) {
            float t0 = __shfl(p0[r], srcA), t1 = __shfl(p1[r], srcA);
            pf[r] = f2bf(sel ? t1 : t0);
            float u0 = __shfl(p0[r], srcB), u1 = __shfl(p1[r], srcB);
            pf[4 + r] = f2bf(sel ? u1 : u0);
        }

        #pragma unroll
        for (int nt = 0; nt < 4; nt++) {
            short8 bv = *(const short8*)(vbase + (size_t)(nt * 16 + l16) * Ss + k0 + quad * 8);
            oc[nt] = __builtin_amdgcn_mfma_f32_16x16x32_bf16(pf, bv, oc[nt], 0, 0, 0);
        }
    }

    lsum += __shfl_xor(lsum, 16);
    lsum += __shfl_xor(lsum, 32);
    float linv[4];
    #pragma unroll
    for (int r = 0; r < 4; r++) linv[r] = 1.f / __shfl(lsum, quad * 4 + r);

    #pragma unroll
    for (int nt = 0; nt < 4; nt++) {
        #pragma unroll
        for (int r = 0; r < 4; r++) {
            int tokq = tb + q0 + quad * 4 + r;
            out[(size_t)tokq * (Hh * DH) + h * DH + nt * 16 + l16] =
                __float2bfloat16(oc[nt][r] * linv[r]);
        }
    }
}

// ---------------------------------------------------------------------------
// Gate: inline fp32 LN2 + softmax + top-2, block-aggregated atomics.
// 256 threads / block, 4 waves; each wave computes 16 tokens (one at a time,
// numerically identical to the per-token single-wave version). Block then
// builds a local per-expert histogram + prefix in LDS and issues ONE
// atomicAdd(&counts[e]) and ONE atomicAdd(&psum[e]) per expert per block
// (vs 10 contended same-line atomics per token before).
#define GT 64   // tokens per block
__global__ __launch_bounds__(256) void gate_kernel(const float* __restrict__ wk,
                                                   const float* __restrict__ g2s,
                                                   const float* __restrict__ g2b,
                                                   const float* __restrict__ Wg,
                                                   const float* __restrict__ bg,
                                                   float* __restrict__ psum,
                                                   int* __restrict__ counts,
                                                   int* __restrict__ bucket,
                                                   int* __restrict__ eidx,
                                                   int* __restrict__ epos,
                                                   float* __restrict__ ew) {
    int t0 = blockIdx.x * GT;
    int wave = threadIdx.x >> 6, lane = threadIdx.x & 63;

    __shared__ float sp[GT][Ee];       // per-token probs (for psum)
    __shared__ int   sel_e[2][GT];     // top-2 expert ids
    __shared__ int   spos[2][GT];      // block-local position within expert bucket
    __shared__ int   lbase[Ee];        // global base from atomicAdd

    for (int i = wave; i < GT; i += 4) {
        int t = t0 + i;
        const float* xr = wk + (size_t)t * Dd;
        float xv[16];
        float s1 = 0.f, sq = 0.f;
        #pragma unroll
        for (int j = 0; j < 16; j++) {
            float v = xr[lane + j * 64];
            xv[j] = v; s1 += v; sq += v * v;
        }
        #pragma unroll
        for (int off = 32; off; off >>= 1) { s1 += __shfl_xor(s1, off); sq += __shfl_xor(sq, off); }
        float mu = s1 * (1.f / Dd), var = sq * (1.f / Dd) - mu * mu;
        float rstd = rsqrtf(var + 1e-6f);
        float acc[Ee] = {};
        #pragma unroll
        for (int j = 0; j < 16; j++) {
            int d = lane + j * 64;
            float xn = (xv[j] - mu) * rstd * g2s[d] + g2b[d];
            const float* wr = Wg + d * Ee;
            #pragma unroll
            for (int e = 0; e < Ee; e++) acc[e] += xn * wr[e];
        }
        #pragma unroll
        for (int e = 0; e < Ee; e++)
            #pragma unroll
            for (int off = 32; off; off >>= 1) acc[e] += __shfl_xor(acc[e], off);
        if (lane == 0) {
            float lg[Ee], mx = -1e30f;
            #pragma unroll
            for (int e = 0; e < Ee; e++) { lg[e] = acc[e] + bg[e]; mx = fmaxf(mx, lg[e]); }
            float p[Ee], ssum = 0.f;
            #pragma unroll
            for (int e = 0; e < Ee; e++) { p[e] = __expf(lg[e] - mx); ssum += p[e]; }
            float ise = 1.f / ssum;
            #pragma unroll
            for (int e = 0; e < Ee; e++) { p[e] *= ise; sp[i][e] = p[e]; }
            int e1 = 0;
            for (int e = 1; e < Ee; e++) if (p[e] > p[e1]) e1 = e;
            int e2 = -1;
            for (int e = 0; e < Ee; e++) if (e != e1 && (e2 < 0 || p[e] > p[e2])) e2 = e;
            sel_e[0][i] = e1; sel_e[1][i] = e2;
            float w1 = p[e1], w2 = p[e2], isw = 1.f / (w1 + w2);
            eidx[2 * t] = e1; ew[2 * t] = w1 * isw;
            eidx[2 * t + 1] = e2; ew[2 * t + 1] = w2 * isw;
        }
    }
    __syncthreads();

    // Phase 2a: per-expert local prefix + single global atomic per expert.
    if (threadIdx.x < Ee) {
        int e = threadIdx.x;
        int local = 0;
        for (int i = 0; i < GT; i++) {
            if (sel_e[0][i] == e) spos[0][i] = local++;
            if (sel_e[1][i] == e) spos[1][i] = local++;
        }
        lbase[e] = atomicAdd(&counts[e], local);
        float ps = 0.f;
        for (int i = 0; i < GT; i++) ps += sp[i][e];
        atomicAdd(&psum[e], ps);
    }
    __syncthreads();

    // Phase 2b: write bucket entries + epos with global base.
    if (threadIdx.x < GT) {
        int i = threadIdx.x, t = t0 + i;
        #pragma unroll
        for (int s = 0; s < 2; s++) {
            int e = sel_e[s][i];
            int pos = lbase[e] + spos[s][i];
            bucket[e * Tt + pos] = t;
            epos[2 * t + s] = pos;
        }
    }
}

__global__ void zero_init(float* psum, int* counts) {
    int i = threadIdx.x;
    if (i < Ee) { psum[i] = 0.f; counts[i] = 0; }
}

__global__ void prefix_kernel(const int* counts, int* bases) {
    if (threadIdx.x == 0) {
        int run = 0;
        for (int e = 0; e < Ee; e++) { bases[e] = run; run += counts[e]; }
    }
}

// out[t] = working[t] + w0*O2[slot0] + w1*O2[slot1]
__global__ __launch_bounds__(256) void combine_out(const float* __restrict__ working,
                                                   const float* __restrict__ O2,
                                                   const int* __restrict__ bases,
                                                   const int* __restrict__ eidx,
                                                   const int* __restrict__ epos,
                                                   const float* __restrict__ ew,
                                                   float* __restrict__ out) {
    int t = blockIdx.x, tid = threadIdx.x;
    int e0 = eidx[2 * t], e1 = eidx[2 * t + 1];
    size_t r0 = (size_t)(bases[e0] + epos[2 * t]) * Dd;
    size_t r1 = (size_t)(bases[e1] + epos[2 * t + 1]) * Dd;
    float w0 = ew[2 * t], w1 = ew[2 * t + 1];
    const float4* wr = (const float4*)(working + (size_t)t * Dd);
    const float4* o0 = (const float4*)(O2 + r0);
    const float4* o1 = (const float4*)(O2 + r1);
    float4* dst = (float4*)(out + (size_t)t * Dd);
    float4 a = wr[tid], x0 = o0[tid], x1 = o1[tid];
    dst[tid] = make_float4(a.x + w0 * x0.x + w1 * x1.x,
                           a.y + w0 * x0.y + w1 * x1.y,
                           a.z + w0 * x0.z + w1 * x1.z,
                           a.w + w0 * x0.w + w1 * x1.w);
}

__global__ void aux_kernel(const int* counts, const float* psum, float* out) {
    if (threadIdx.x == 0 && blockIdx.x == 0) {
        float a = 0.f;
        for (int e = 0; e < Ee; e++)
            a += (counts[e] * (1.f / Tt)) * (psum[e] * (1.f / Tt));
        out[0] = 0.01f * (float)Ee * a;
    }
}

// ---------------------------------------------------------------------------
extern "C" void kernel_launch(void* const* d_in, const int* in_sizes, int n_in,
                              void* d_out, int out_size, void* d_ws, size_t ws_size,
                              hipStream_t stream) {
    const float* x     = (const float*)d_in[0];
    const float* ln1_s = (const float*)d_in[1];
    const float* ln1_b = (const float*)d_in[2];
    const float* Wq    = (const float*)d_in[3];
    const float* bq    = (const float*)d_in[4];
    const float* Wk    = (const float*)d_in[5];
    const float* bk    = (const float*)d_in[6];
    const float* Wv    = (const float*)d_in[7];
    const float* bv    = (const float*)d_in[8];
    const float* Wo    = (const float*)d_in[9];
    const float* bo    = (const float*)d_in[10];
    const float* ln2_s = (const float*)d_in[11];
    const float* ln2_b = (const float*)d_in[12];
    const float* Wg    = (const float*)d_in[13];
    const float* bg    = (const float*)d_in[14];
    const float* W1    = (const float*)d_in[15];
    const float* b1    = (const float*)d_in[16];
    const float* W2    = (const float*)d_in[17];
    const float* b2    = (const float*)d_in[18];

    const size_t MBy = 1u << 20;
    char* base = (char*)d_ws;
    __hip_bfloat16* attn_in = (__hip_bfloat16*)(base);             // 0-8   (also attn_out)
    __hip_bfloat16* qbf     = (__hip_bfloat16*)(base + 8 * MBy);   // 8-16
    __hip_bfloat16* kbf     = (__hip_bfloat16*)(base + 16 * MBy);  // 16-24
    __hip_bfloat16* Vt      = (__hip_bfloat16*)(base + 24 * MBy);  // 24-32
    float*          working = (float*)(base + 32 * MBy);           // 32-48
    __hip_bfloat16* ffn_in  = (__hip_bfloat16*)(base + 48 * MBy);  // 48-56
    __hip_bfloat16* Hbuf    = (__hip_bfloat16*)(base + 56 * MBy);  // 56-120 (8192x4096 bf16)
    float*          O2      = (float*)(base);                      // 0-32  (overlays dead attn bufs)
    __hip_bfloat16* WT      = (__hip_bfloat16*)(base + 120 * MBy); // 120-184 shared (W1T then W2T)
    __hip_bfloat16* WqT     = (__hip_bfloat16*)(base + 120 * MBy); // QKVO transposes (dead before WT)
    __hip_bfloat16* WkT     = (__hip_bfloat16*)(base + 122 * MBy);
    __hip_bfloat16* WvT     = (__hip_bfloat16*)(base + 124 * MBy);
    __hip_bfloat16* WoT     = (__hip_bfloat16*)(base + 126 * MBy);
    char* rt = base + 184 * MBy;
    int*   bucket = (int*)rt;                        // 8*4096 ints
    // counts / bases / psum each on their own 256B line so the two atomic
    // streams (counts, psum) don't serialize against each other.
    int*   counts = (int*)(rt + Ee * Tt * 4);
    int*   bases  = counts + 64;
    float* psum   = (float*)(bases + 64);
    int*   eidx   = (int*)(psum + 64);               // 2*Tt
    int*   epos   = eidx + 2 * Tt;
    float* ew     = (float*)(epos + 2 * Tt);

    float* out  = (float*)d_out;
    float* auxp = out + (size_t)Tt * Dd;

    zero_init<<<1, 64, 0, stream>>>(psum, counts);
    transpose_qkvo<<<dim3(32, 32, 4), 256, 0, stream>>>(Wq, Wk, Wv, Wo, WqT, WkT, WvT, WoT);
    ln_kernel<<<Tt, 256, 0, stream>>>(x, ln1_s, ln1_b, attn_in);

    dim3 gqkv(Dd / 128, Tt / 128);
    gemm_mfma<0><<<gqkv, 256, 0, stream>>>(attn_in, WqT, bq, qbf, Tt, Dd, Dd,
                                           nullptr, nullptr, nullptr, nullptr);
    gemm_mfma<0><<<gqkv, 256, 0, stream>>>(attn_in, WkT, bk, kbf, Tt, Dd, Dd,
                                           nullptr, nullptr, nullptr, nullptr);
    gemm_mfma<4><<<gqkv, 256, 0, stream>>>(attn_in, WvT, bv, Vt, Tt, Dd, Dd,
                                           nullptr, nullptr, nullptr, nullptr);

    attn_mfma<<<dim3(Ss / 64, Hh, Bb), 256, 0, stream>>>(qbf, kbf, Vt, attn_in);

    gemm_mfma<1><<<gqkv, 256, 0, stream>>>(attn_in, WoT, bo, working, Tt, Dd, Dd,
                                           nullptr, nullptr, nullptr, x);

    ln_kernel<<<Tt, 256, 0, stream>>>(working, ln2_s, ln2_b, ffn_in);
    gate_kernel<<<Tt / GT, 256, 0, stream>>>(working, ln2_s, ln2_b, Wg, bg,
                                             psum, counts, bucket, eidx, epos, ew);
    prefix_kernel<<<1, 64, 0, stream>>>(counts, bases);

    transpose_we<<<dim3(FH / 32, Dd / 32, Ee), 256, 0, stream>>>(W1, WT, Dd, FH);
    gemm_mfma<2><<<dim3(FH / 128, Tt / 128, Ee), 256, 0, stream>>>(
        ffn_in, WT, b1, Hbuf, Tt, FH, Dd, bucket, counts, bases, nullptr);
    transpose_we<<<dim3(Dd / 32, FH / 32, Ee), 256, 0, stream>>>(W2, WT, FH, Dd);
    gemm_mfma<3><<<dim3(Dd / 128, Tt / 128, Ee), 256, 0, stream>>>(
        Hbuf, WT, b2, O2, Tt, Dd, FH, bucket, counts, bases, nullptr);

    combine_out<<<Tt, 256, 0, stream>>>(working, O2, bases, eidx, epos, ew, out);
    aux_kernel<<<1, 64, 0, stream>>>(counts, psum, auxp);
}